// Round 2
// baseline (575.369 us; speedup 1.0000x reference)
//
#include <hip/hip_runtime.h>
#include <stdint.h>
#include <stddef.h>

#define NN 1000000
#define KT 9
#define NEG_SLOPE 0.01f
#define BN_EPS 1e-5f
#define NTILES (NN / 16)

typedef float f32x4 __attribute__((ext_vector_type(4)));
typedef short bf16x8 __attribute__((ext_vector_type(8)));

__device__ __forceinline__ short f2bf(float f) {
    union { float f; uint32_t u; } x; x.f = f;
    uint32_t u = x.u;
    uint32_t r = (u + 0x7FFFu + ((u >> 16) & 1u)) >> 16;   // RNE
    return (short)(r & 0xFFFFu);
}

// ws layout (floats): [0..31] sum[c], [32..63] sumsq[c], [64..95] scale[c],
// [96..127] shift[c], [128] mask-mode flag (int: 0=u8, 1=i32, 2=f32)

__global__ void detect_mask_mode_kernel(const uint32_t* __restrict__ mask,
                                        int* __restrict__ flag) {
    const int i = threadIdx.x;   // 64 threads, 4 words each
    bool anyf = false, anybig = false;
    #pragma unroll
    for (int j = 0; j < 4; ++j) {
        uint32_t w = mask[i * 4 + j];
        if (w == 0x3F800000u) anyf = true;
        else if (w > 1u) anybig = true;
    }
    unsigned long long bf = __ballot(anyf);
    unsigned long long bb = __ballot(anybig);
    if (i == 0) *flag = bf ? 2 : (bb ? 0 : 1);
}

template <int MODE>
__device__ __forceinline__ void conv_loop(
    const float* __restrict__ feat, const int* __restrict__ nidx,
    const void* __restrict__ nmask, float* __restrict__ out,
    const short* wlds, int lane, int col, int kg, int k0,
    int gwave, int nwave, float& s0, float& s1, float& q0, float& q1)
{
    const uint8_t* m8  = (const uint8_t*)nmask;
    const int*     m32 = (const int*)nmask;
    const float*   mf  = (const float*)nmask;

    for (int t = gwave; t < NTILES; t += nwave) {
        const int vbase = t * 16;
        const int v = vbase + col;

        // Phase A: hoist idx + mask for all taps (9-deep MLP)
        int  ids[KT];
        bool act[KT];
        #pragma unroll
        for (int k = 0; k < KT; ++k) {
            const int e = k * NN + v;
            ids[k] = nidx[e];
            if (MODE == 0)      act[k] = (m8[e]  != 0);
            else if (MODE == 1) act[k] = (m32[e] != 0);
            else                act[k] = (mf[e]  != 0.0f);
        }

        f32x4 acc0 = {0.f, 0.f, 0.f, 0.f};
        f32x4 acc1 = {0.f, 0.f, 0.f, 0.f};
        #pragma unroll
        for (int k = 0; k < KT; ++k) {
            const float* src = feat + (size_t)ids[k] * 32 + k0;
            const f32x4 lo = *(const f32x4*)(src);       // unconditional gather
            const f32x4 hi = *(const f32x4*)(src + 4);
            bf16x8 a;
            #pragma unroll
            for (int j = 0; j < 4; ++j) { a[j] = f2bf(lo[j]); a[j + 4] = f2bf(hi[j]); }
            if (!act[k]) a = (bf16x8){0, 0, 0, 0, 0, 0, 0, 0};   // cndmask-zero
            const bf16x8 b0 = *(const bf16x8*)&wlds[((k * 2 + 0) * 64 + lane) * 8];
            const bf16x8 b1 = *(const bf16x8*)&wlds[((k * 2 + 1) * 64 + lane) * 8];
            acc0 = __builtin_amdgcn_mfma_f32_16x16x32_bf16(a, b0, acc0, 0, 0, 0);
            acc1 = __builtin_amdgcn_mfma_f32_16x16x32_bf16(a, b1, acc1, 0, 0, 0);
        }

        // D layout: col=lane&15, row=(lane>>4)*4+reg (m89-verified)
        #pragma unroll
        for (int r = 0; r < 4; ++r) {
            const int row = vbase + kg * 4 + r;
            float y0 = acc0[r]; y0 = (y0 >= 0.f) ? y0 : NEG_SLOPE * y0;
            float y1 = acc1[r]; y1 = (y1 >= 0.f) ? y1 : NEG_SLOPE * y1;
            out[row * 32 + col]      = y0;
            out[row * 32 + 16 + col] = y1;
            s0 += y0; q0 += y0 * y0;
            s1 += y1; q1 += y1 * y1;
        }
    }
}

__global__ __launch_bounds__(256, 6) void spconv_kernel(
    const float* __restrict__ feat, const float* __restrict__ wgt,
    const int* __restrict__ nidx, const void* __restrict__ nmask,
    const int* __restrict__ flag, float* __restrict__ out,
    float* __restrict__ stats)
{
    // Stage bf16 B-fragments in LDS: [k][h][lane] -> 8 contiguous bf16 (16B)
    // frag element j at lane(col,kg) = W[k][kg*8+j][h*16+col]
    __shared__ short wlds[KT * 2 * 64 * 8];   // 18 KiB
    const int tid = threadIdx.x;
    for (int s = tid; s < KT * 2 * 64; s += 256) {
        const int k    = s >> 7;       // /(2*64)
        const int rem  = s & 127;
        const int h    = rem >> 6;
        const int l2   = rem & 63;
        const int kg2  = l2 >> 4;
        const int col2 = l2 & 15;
        #pragma unroll
        for (int j = 0; j < 8; ++j)
            wlds[s * 8 + j] = f2bf(wgt[k * 1024 + (kg2 * 8 + j) * 32 + h * 16 + col2]);
    }
    __syncthreads();

    const int mode = *flag;
    const int lane = threadIdx.x & 63;
    const int w    = threadIdx.x >> 6;
    const int col  = lane & 15;
    const int kg   = lane >> 4;
    const int k0   = kg * 8;

    const int gwave = blockIdx.x * 4 + w;
    const int nwave = gridDim.x * 4;

    float s0 = 0.f, s1 = 0.f, q0 = 0.f, q1 = 0.f;
    if (mode == 0)
        conv_loop<0>(feat, nidx, nmask, out, wlds, lane, col, kg, k0, gwave, nwave, s0, s1, q0, q1);
    else if (mode == 1)
        conv_loop<1>(feat, nidx, nmask, out, wlds, lane, col, kg, k0, gwave, nwave, s0, s1, q0, q1);
    else
        conv_loop<2>(feat, nidx, nmask, out, wlds, lane, col, kg, k0, gwave, nwave, s0, s1, q0, q1);

    // reduce across the 4 lanes sharing `col` (l, l^16, l^32, l^48)
    s0 += __shfl_xor(s0, 16); s0 += __shfl_xor(s0, 32);
    s1 += __shfl_xor(s1, 16); s1 += __shfl_xor(s1, 32);
    q0 += __shfl_xor(q0, 16); q0 += __shfl_xor(q0, 32);
    q1 += __shfl_xor(q1, 16); q1 += __shfl_xor(q1, 32);

    __shared__ float red[4][64];
    if (lane < 16) {
        red[w][col]      = s0;  red[w][col + 16] = s1;
        red[w][col + 32] = q0;  red[w][col + 48] = q1;
    }
    __syncthreads();
    if (threadIdx.x < 64) {
        float tot = red[0][threadIdx.x] + red[1][threadIdx.x]
                  + red[2][threadIdx.x] + red[3][threadIdx.x];
        atomicAdd(&stats[threadIdx.x], tot);
    }
}

__global__ void bn_stats_kernel(const float* __restrict__ stats,
                                const float* __restrict__ gamma,
                                const float* __restrict__ beta,
                                float* __restrict__ sc) {
    int c = threadIdx.x;
    if (c < 32) {
        const float inv_n = 1.0f / (float)NN;
        float mean = stats[c] * inv_n;
        float var  = stats[32 + c] * inv_n - mean * mean;
        float s    = gamma[c] * rsqrtf(var + BN_EPS);
        sc[c]      = s;
        sc[32 + c] = beta[c] - mean * s;
    }
}

__global__ __launch_bounds__(256) void bn_apply_kernel(float* __restrict__ out,
                                                       const float* __restrict__ sc) {
    __shared__ float s[32], b[32];
    if (threadIdx.x < 32)      s[threadIdx.x] = sc[threadIdx.x];
    else if (threadIdx.x < 64) b[threadIdx.x - 32] = sc[threadIdx.x];
    __syncthreads();
    f32x4* o4 = (f32x4*)out;
    const int total4 = NN * 32 / 4;
    for (int i = blockIdx.x * blockDim.x + threadIdx.x; i < total4;
         i += gridDim.x * blockDim.x) {
        f32x4 v = o4[i];
        const int c0 = (i & 7) * 4;
        v[0] = v[0] * s[c0]     + b[c0];
        v[1] = v[1] * s[c0 + 1] + b[c0 + 1];
        v[2] = v[2] * s[c0 + 2] + b[c0 + 2];
        v[3] = v[3] * s[c0 + 3] + b[c0 + 3];
        o4[i] = v;
    }
}

extern "C" void kernel_launch(void* const* d_in, const int* in_sizes, int n_in,
                              void* d_out, int out_size, void* d_ws, size_t ws_size,
                              hipStream_t stream) {
    const float* feat  = (const float*)d_in[0];
    const float* wgt   = (const float*)d_in[1];
    const float* gamma = (const float*)d_in[2];
    const float* beta  = (const float*)d_in[3];
    const int*   nidx  = (const int*)d_in[4];
    const void*  nmask = d_in[5];
    float* out = (float*)d_out;
    float* ws  = (float*)d_ws;

    hipMemsetAsync(ws, 0, 64 * sizeof(float), stream);   // zero stats accumulators
    detect_mask_mode_kernel<<<1, 64, 0, stream>>>((const uint32_t*)nmask,
                                                  (int*)(ws + 128));
    spconv_kernel<<<1536, 256, 0, stream>>>(feat, wgt, nidx, nmask,
                                            (const int*)(ws + 128), out, ws);
    bn_stats_kernel<<<1, 64, 0, stream>>>(ws, gamma, beta, ws + 64);
    bn_apply_kernel<<<4096, 256, 0, stream>>>(out, ws + 64);
}

// Round 5
// 557.483 us; speedup vs baseline: 1.0321x; 1.0321x over previous
//
#include <hip/hip_runtime.h>
#include <stdint.h>
#include <stddef.h>

#define NN 1000000
#define KT 9
#define NEG_SLOPE 0.01f
#define BN_EPS 1e-5f
#define NTILES (NN / 16)

typedef float f32x4 __attribute__((ext_vector_type(4)));
typedef short bf16x8 __attribute__((ext_vector_type(8)));

// ws layout (bytes):
//   [0, 64MB)        feat_bf16  [NN][32] bf16
//   [64MB, 128MB)    y_bf16     [NN][32] bf16
//   [128MB, ...)     meta floats: [0..31] sum, [32..63] sumsq,
//                    [64..127] scale/shift, [128] mask-mode flag (int)
#define META_FLOATS 192
#define WS_NEEDED (((size_t)128 << 20) + META_FLOATS * 4)

__device__ __forceinline__ short f2bf(float f) {
    union { float f; uint32_t u; } x; x.f = f;
    uint32_t u = x.u;
    uint32_t r = (u + 0x7FFFu + ((u >> 16) & 1u)) >> 16;   // RNE
    return (short)(r & 0xFFFFu);
}
__device__ __forceinline__ float bf2f(unsigned short s) {
    union { uint32_t u; float f; } x; x.u = ((uint32_t)s) << 16;
    return x.f;
}

// mode: 0=u8, 1=i32, 2=f32  (proven-correct runtime detector from rounds 1-2)
__global__ void detect_mask_mode_kernel(const uint32_t* __restrict__ mask,
                                        int* __restrict__ flag) {
    const int i = threadIdx.x;   // 64 threads, 4 words each
    bool anyf = false, anybig = false;
    #pragma unroll
    for (int j = 0; j < 4; ++j) {
        uint32_t w = mask[i * 4 + j];
        if (w == 0x3F800000u) anyf = true;
        else if (w > 1u) anybig = true;
    }
    unsigned long long bfm = __ballot(anyf);
    unsigned long long bbm = __ballot(anybig);
    if (i == 0) *flag = bfm ? 2 : (bbm ? 0 : 1);
}

__global__ __launch_bounds__(256) void cvt_feat_kernel(
    const float* __restrict__ in, unsigned short* __restrict__ outb) {
    const int tot = NN * 32 / 8;
    for (int i = blockIdx.x * 256 + threadIdx.x; i < tot; i += gridDim.x * 256) {
        const f32x4 a = ((const f32x4*)in)[i * 2];
        const f32x4 b = ((const f32x4*)in)[i * 2 + 1];
        bf16x8 o;
        #pragma unroll
        for (int j = 0; j < 4; ++j) { o[j] = f2bf(a[j]); o[j + 4] = f2bf(b[j]); }
        ((bf16x8*)outb)[i] = o;
    }
}

// ---------- shared helpers ----------
__device__ __forceinline__ void stage_weights(const float* __restrict__ wgt,
                                              short* wlds) {
    const int tid = threadIdx.x;
    for (int s = tid; s < KT * 2 * 64; s += 256) {
        const int k    = s >> 7;
        const int rem  = s & 127;
        const int h    = rem >> 6;
        const int l2   = rem & 63;
        const int kg2  = l2 >> 4;
        const int col2 = l2 & 15;
        #pragma unroll
        for (int j = 0; j < 8; ++j)
            wlds[s * 8 + j] = f2bf(wgt[k * 1024 + (kg2 * 8 + j) * 32 + h * 16 + col2]);
    }
}

template <int MODE>
__device__ __forceinline__ bool mask_at(const void* nmask, int e) {
    if (MODE == 0) return ((const uint8_t*)nmask)[e] != 0;
    if (MODE == 1) return ((const int*)nmask)[e] != 0;
    return ((const float*)nmask)[e] != 0.0f;
}

__device__ __forceinline__ void final_reduce(float s0, float s1, float q0,
                                             float q1, int lane, int w,
                                             float* __restrict__ stats) {
    s0 += __shfl_xor(s0, 16); s0 += __shfl_xor(s0, 32);
    s1 += __shfl_xor(s1, 16); s1 += __shfl_xor(s1, 32);
    q0 += __shfl_xor(q0, 16); q0 += __shfl_xor(q0, 32);
    q1 += __shfl_xor(q1, 16); q1 += __shfl_xor(q1, 32);
    __shared__ float red[4][64];
    const int col = lane & 15;
    if (lane < 16) {
        red[w][col]      = s0;  red[w][col + 16] = s1;
        red[w][col + 32] = q0;  red[w][col + 48] = q1;
    }
    __syncthreads();
    if (threadIdx.x < 64) {
        float tot = red[0][threadIdx.x] + red[1][threadIdx.x]
                  + red[2][threadIdx.x] + red[3][threadIdx.x];
        atomicAdd(&stats[threadIdx.x], tot);
    }
}

// ---------- fast path: bf16 features, bf16 y ----------
template <int MODE>
__device__ __forceinline__ void conv_bf_loop(
    const unsigned short* __restrict__ featb, const int* __restrict__ nidx,
    const void* __restrict__ nmask, unsigned short* __restrict__ yb,
    const short* wlds, int lane, int col, int kg, int k0,
    int gwave, int nwave, float& s0, float& s1, float& q0, float& q1)
{
    for (int t = gwave; t < NTILES; t += nwave) {
        const int vbase = t * 16;
        const int v = vbase + col;

        int  ids[KT];
        bool act[KT];
        #pragma unroll
        for (int k = 0; k < KT; ++k) {
            const int e = k * NN + v;
            ids[k] = nidx[e];
            act[k] = mask_at<MODE>(nmask, e);
        }

        f32x4 acc0 = {0.f, 0.f, 0.f, 0.f};
        f32x4 acc1 = {0.f, 0.f, 0.f, 0.f};
        #pragma unroll
        for (int k = 0; k < KT; ++k) {
            bf16x8 a = {0, 0, 0, 0, 0, 0, 0, 0};
            if (act[k])
                a = *(const bf16x8*)(featb + (size_t)ids[k] * 32 + k0);
            const bf16x8 b0 = *(const bf16x8*)&wlds[((k * 2 + 0) * 64 + lane) * 8];
            const bf16x8 b1 = *(const bf16x8*)&wlds[((k * 2 + 1) * 64 + lane) * 8];
            acc0 = __builtin_amdgcn_mfma_f32_16x16x32_bf16(a, b0, acc0, 0, 0, 0);
            acc1 = __builtin_amdgcn_mfma_f32_16x16x32_bf16(a, b1, acc1, 0, 0, 0);
        }

        // D layout: col=lane&15, row=(lane>>4)*4+reg (m89-verified)
        #pragma unroll
        for (int r = 0; r < 4; ++r) {
            const int row = vbase + kg * 4 + r;
            float y0 = acc0[r]; y0 = (y0 >= 0.f) ? y0 : NEG_SLOPE * y0;
            float y1 = acc1[r]; y1 = (y1 >= 0.f) ? y1 : NEG_SLOPE * y1;
            yb[row * 32 + col]      = (unsigned short)f2bf(y0);
            yb[row * 32 + 16 + col] = (unsigned short)f2bf(y1);
            s0 += y0; q0 += y0 * y0;
            s1 += y1; q1 += y1 * y1;
        }
    }
}

__global__ __launch_bounds__(256, 8) void spconv_bf_kernel(
    const unsigned short* __restrict__ featb, const float* __restrict__ wgt,
    const int* __restrict__ nidx, const void* __restrict__ nmask,
    const int* __restrict__ flag, unsigned short* __restrict__ yb,
    float* __restrict__ stats)
{
    __shared__ short wlds[KT * 2 * 64 * 8];
    stage_weights(wgt, wlds);
    __syncthreads();

    const int mode = *flag;            // wave-uniform runtime dispatch
    const int lane = threadIdx.x & 63;
    const int w    = threadIdx.x >> 6;
    const int col  = lane & 15;
    const int kg   = lane >> 4;
    const int k0   = kg * 8;

    const int gwave = blockIdx.x * 4 + w;
    const int nwave = gridDim.x * 4;

    float s0 = 0.f, s1 = 0.f, q0 = 0.f, q1 = 0.f;
    if (mode == 0)
        conv_bf_loop<0>(featb, nidx, nmask, yb, wlds, lane, col, kg, k0, gwave, nwave, s0, s1, q0, q1);
    else if (mode == 1)
        conv_bf_loop<1>(featb, nidx, nmask, yb, wlds, lane, col, kg, k0, gwave, nwave, s0, s1, q0, q1);
    else
        conv_bf_loop<2>(featb, nidx, nmask, yb, wlds, lane, col, kg, k0, gwave, nwave, s0, s1, q0, q1);

    final_reduce(s0, s1, q0, q1, lane, w, stats);
}

// ---------- fallback path: f32 features, f32 y in d_out ----------
template <int MODE>
__device__ __forceinline__ void conv_f32_loop(
    const float* __restrict__ feat, const int* __restrict__ nidx,
    const void* __restrict__ nmask, float* __restrict__ out,
    const short* wlds, int lane, int col, int kg, int k0,
    int gwave, int nwave, float& s0, float& s1, float& q0, float& q1)
{
    for (int t = gwave; t < NTILES; t += nwave) {
        const int vbase = t * 16;
        const int v = vbase + col;

        int  ids[KT];
        bool act[KT];
        #pragma unroll
        for (int k = 0; k < KT; ++k) {
            const int e = k * NN + v;
            ids[k] = nidx[e];
            act[k] = mask_at<MODE>(nmask, e);
        }

        f32x4 acc0 = {0.f, 0.f, 0.f, 0.f};
        f32x4 acc1 = {0.f, 0.f, 0.f, 0.f};
        #pragma unroll
        for (int k = 0; k < KT; ++k) {
            bf16x8 a = {0, 0, 0, 0, 0, 0, 0, 0};
            if (act[k]) {
                const float* src = feat + (size_t)ids[k] * 32 + k0;
                const f32x4 lo = *(const f32x4*)(src);
                const f32x4 hi = *(const f32x4*)(src + 4);
                #pragma unroll
                for (int j = 0; j < 4; ++j) { a[j] = f2bf(lo[j]); a[j + 4] = f2bf(hi[j]); }
            }
            const bf16x8 b0 = *(const bf16x8*)&wlds[((k * 2 + 0) * 64 + lane) * 8];
            const bf16x8 b1 = *(const bf16x8*)&wlds[((k * 2 + 1) * 64 + lane) * 8];
            acc0 = __builtin_amdgcn_mfma_f32_16x16x32_bf16(a, b0, acc0, 0, 0, 0);
            acc1 = __builtin_amdgcn_mfma_f32_16x16x32_bf16(a, b1, acc1, 0, 0, 0);
        }

        #pragma unroll
        for (int r = 0; r < 4; ++r) {
            const int row = vbase + kg * 4 + r;
            float y0 = acc0[r]; y0 = (y0 >= 0.f) ? y0 : NEG_SLOPE * y0;
            float y1 = acc1[r]; y1 = (y1 >= 0.f) ? y1 : NEG_SLOPE * y1;
            out[row * 32 + col]      = y0;
            out[row * 32 + 16 + col] = y1;
            s0 += y0; q0 += y0 * y0;
            s1 += y1; q1 += y1 * y1;
        }
    }
}

__global__ __launch_bounds__(256, 6) void spconv_f32_kernel(
    const float* __restrict__ feat, const float* __restrict__ wgt,
    const int* __restrict__ nidx, const void* __restrict__ nmask,
    const int* __restrict__ flag, float* __restrict__ out,
    float* __restrict__ stats)
{
    __shared__ short wlds[KT * 2 * 64 * 8];
    stage_weights(wgt, wlds);
    __syncthreads();

    const int mode = *flag;
    const int lane = threadIdx.x & 63;
    const int w    = threadIdx.x >> 6;
    const int col  = lane & 15;
    const int kg   = lane >> 4;
    const int k0   = kg * 8;

    const int gwave = blockIdx.x * 4 + w;
    const int nwave = gridDim.x * 4;

    float s0 = 0.f, s1 = 0.f, q0 = 0.f, q1 = 0.f;
    if (mode == 0)
        conv_f32_loop<0>(feat, nidx, nmask, out, wlds, lane, col, kg, k0, gwave, nwave, s0, s1, q0, q1);
    else if (mode == 1)
        conv_f32_loop<1>(feat, nidx, nmask, out, wlds, lane, col, kg, k0, gwave, nwave, s0, s1, q0, q1);
    else
        conv_f32_loop<2>(feat, nidx, nmask, out, wlds, lane, col, kg, k0, gwave, nwave, s0, s1, q0, q1);

    final_reduce(s0, s1, q0, q1, lane, w, stats);
}

__global__ void bn_stats_kernel(const float* __restrict__ stats,
                                const float* __restrict__ gamma,
                                const float* __restrict__ beta,
                                float* __restrict__ sc) {
    int c = threadIdx.x;
    if (c < 32) {
        const float inv_n = 1.0f / (float)NN;
        float mean = stats[c] * inv_n;
        float var  = stats[32 + c] * inv_n - mean * mean;
        float s    = gamma[c] * rsqrtf(var + BN_EPS);
        sc[c]      = s;
        sc[32 + c] = beta[c] - mean * s;
    }
}

__global__ __launch_bounds__(256) void bn_apply_bf_kernel(
    const unsigned short* __restrict__ yb, float* __restrict__ out,
    const float* __restrict__ sc) {
    __shared__ float s[32], b[32];
    if (threadIdx.x < 32)      s[threadIdx.x] = sc[threadIdx.x];
    else if (threadIdx.x < 64) b[threadIdx.x - 32] = sc[threadIdx.x];
    __syncthreads();
    const int tot = NN * 32 / 8;
    for (int i = blockIdx.x * blockDim.x + threadIdx.x; i < tot;
         i += gridDim.x * blockDim.x) {
        const bf16x8 v = ((const bf16x8*)yb)[i];
        const int c0 = (i & 3) * 8;
        f32x4 o0, o1;
        #pragma unroll
        for (int j = 0; j < 4; ++j) {
            o0[j] = bf2f((unsigned short)v[j])     * s[c0 + j]     + b[c0 + j];
            o1[j] = bf2f((unsigned short)v[j + 4]) * s[c0 + j + 4] + b[c0 + j + 4];
        }
        ((f32x4*)out)[i * 2]     = o0;
        ((f32x4*)out)[i * 2 + 1] = o1;
    }
}

__global__ __launch_bounds__(256) void bn_apply_f32_kernel(
    float* __restrict__ out, const float* __restrict__ sc) {
    __shared__ float s[32], b[32];
    if (threadIdx.x < 32)      s[threadIdx.x] = sc[threadIdx.x];
    else if (threadIdx.x < 64) b[threadIdx.x - 32] = sc[threadIdx.x];
    __syncthreads();
    f32x4* o4 = (f32x4*)out;
    const int total4 = NN * 32 / 4;
    for (int i = blockIdx.x * blockDim.x + threadIdx.x; i < total4;
         i += gridDim.x * blockDim.x) {
        f32x4 v = o4[i];
        const int c0 = (i & 7) * 4;
        #pragma unroll
        for (int j = 0; j < 4; ++j) v[j] = v[j] * s[c0 + j] + b[c0 + j];
        o4[i] = v;
    }
}

extern "C" void kernel_launch(void* const* d_in, const int* in_sizes, int n_in,
                              void* d_out, int out_size, void* d_ws, size_t ws_size,
                              hipStream_t stream) {
    const float* feat  = (const float*)d_in[0];
    const float* wgt   = (const float*)d_in[1];
    const float* gamma = (const float*)d_in[2];
    const float* beta  = (const float*)d_in[3];
    const int*   nidx  = (const int*)d_in[4];
    const void*  nmask = d_in[5];
    float* out = (float*)d_out;

    if (ws_size >= WS_NEEDED) {
        unsigned short* featb = (unsigned short*)d_ws;
        unsigned short* yb    = (unsigned short*)((char*)d_ws + ((size_t)64 << 20));
        float* meta           = (float*)((char*)d_ws + ((size_t)128 << 20));
        int*   flag           = (int*)(meta + 128);

        hipMemsetAsync(meta, 0, 64 * sizeof(float), stream);
        detect_mask_mode_kernel<<<1, 64, 0, stream>>>((const uint32_t*)nmask, flag);
        cvt_feat_kernel<<<2048, 256, 0, stream>>>(feat, featb);
        spconv_bf_kernel<<<2048, 256, 0, stream>>>(featb, wgt, nidx, nmask,
                                                   flag, yb, meta);
        bn_stats_kernel<<<1, 64, 0, stream>>>(meta, gamma, beta, meta + 64);
        bn_apply_bf_kernel<<<4096, 256, 0, stream>>>(yb, out, meta + 64);
    } else {
        float* meta = (float*)d_ws;
        int*   flag = (int*)(meta + 128);
        hipMemsetAsync(meta, 0, 64 * sizeof(float), stream);
        detect_mask_mode_kernel<<<1, 64, 0, stream>>>((const uint32_t*)nmask, flag);
        spconv_f32_kernel<<<1536, 256, 0, stream>>>(feat, wgt, nidx, nmask,
                                                    flag, out, meta);
        bn_stats_kernel<<<1, 64, 0, stream>>>(meta, gamma, beta, meta + 64);
        bn_apply_f32_kernel<<<4096, 256, 0, stream>>>(out, meta + 64);
    }
}

// Round 7
// 429.375 us; speedup vs baseline: 1.3400x; 1.2984x over previous
//
#include <hip/hip_runtime.h>
#include <stdint.h>
#include <stddef.h>

#define NN 1000000
#define KT 9
#define NEG_SLOPE 0.01f
#define BN_EPS 1e-5f
#define NTILES (NN / 16)

#define CVT_BLOCKS 2048
#define PK_BLOCKS 1024
#define PREP_BLOCKS (CVT_BLOCKS + PK_BLOCKS)
#define CONV_BLOCKS 2048
#define APPLY_BLOCKS 4096
#define REPS 8

typedef float f32x4 __attribute__((ext_vector_type(4)));
typedef int   i32x4 __attribute__((ext_vector_type(4)));
typedef short bf16x8 __attribute__((ext_vector_type(8)));

// ws layout (fast path): [0,64MB) feat_bf16 [NN][32]; [64MB,128MB) y_bf16;
//   at 128MB: sc[64] floats (scale/shift).  (same WS_NEEDED as r5 - proven)
// d_out scratch (fast path): ints [0,9M) = pidx; floats [9M, 9M+512) = stats
//   replicas (8 x {sum[32],sumsq[32]}). Both dead before bn_apply overwrites.
#define META_FLOATS 192
#define WS_NEEDED (((size_t)128 << 20) + META_FLOATS * 4)
#define STATS_F_OFF 9000000   // float index into d_out

__device__ __forceinline__ short f2bf(float f) {
    union { float f; uint32_t u; } x; x.f = f;
    uint32_t u = x.u;
    uint32_t r = (u + 0x7FFFu + ((u >> 16) & 1u)) >> 16;   // RNE
    return (short)(r & 0xFFFFu);
}
__device__ __forceinline__ float bf2f(unsigned short s) {
    union { uint32_t u; float f; } x; x.u = ((uint32_t)s) << 16;
    return x.f;
}

// mode: 0=u8, 1=i32, 2=f32 (detector proven in r1-r2/r5)
__device__ __forceinline__ int block_detect_mode(const uint32_t* __restrict__ mask) {
    __shared__ int md;
    if (threadIdx.x < 64) {
        bool anyf = false, anybig = false;
        #pragma unroll
        for (int j = 0; j < 4; ++j) {
            uint32_t w = mask[threadIdx.x * 4 + j];
            if (w == 0x3F800000u) anyf = true;
            else if (w > 1u) anybig = true;
        }
        unsigned long long bfm = __ballot(anyf);
        unsigned long long bbm = __ballot(anybig);
        if (threadIdx.x == 0) md = bfm ? 2 : (bbm ? 0 : 1);
    }
    __syncthreads();
    return md;
}

template <int MODE>
__device__ __forceinline__ void pack_loop(const int* __restrict__ nidx,
                                          const void* __restrict__ nmask,
                                          int* __restrict__ pidx, int bid) {
    const int tot4 = KT * NN / 4;   // 2,250,000
    for (int i = bid * 256 + threadIdx.x; i < tot4; i += PK_BLOCKS * 256) {
        const i32x4 id4 = __builtin_nontemporal_load((const i32x4*)nidx + i);
        i32x4 o;
        if (MODE == 0) {
            const uint32_t mw = __builtin_nontemporal_load((const uint32_t*)nmask + i);
            #pragma unroll
            for (int j = 0; j < 4; ++j) o[j] = ((mw >> (8 * j)) & 0xFFu) ? id4[j] : -1;
        } else if (MODE == 1) {
            const i32x4 m4 = __builtin_nontemporal_load((const i32x4*)nmask + i);
            #pragma unroll
            for (int j = 0; j < 4; ++j) o[j] = m4[j] ? id4[j] : -1;
        } else {
            const f32x4 m4 = __builtin_nontemporal_load((const f32x4*)nmask + i);
            #pragma unroll
            for (int j = 0; j < 4; ++j) o[j] = (m4[j] != 0.0f) ? id4[j] : -1;
        }
        ((i32x4*)pidx)[i] = o;
    }
}

// prep: blocks [0,CVT_BLOCKS) convert features f32->bf16; rest pack idx+mask.
__global__ __launch_bounds__(256) void prep_kernel(
    const float* __restrict__ feat, unsigned short* __restrict__ featb,
    const int* __restrict__ nidx, const void* __restrict__ nmask,
    int* __restrict__ pidx)
{
    if (blockIdx.x < CVT_BLOCKS) {
        const int tot = NN * 32 / 8;   // 4,000,000
        for (int i = blockIdx.x * 256 + threadIdx.x; i < tot; i += CVT_BLOCKS * 256) {
            const f32x4 a = __builtin_nontemporal_load((const f32x4*)feat + i * 2);
            const f32x4 b = __builtin_nontemporal_load((const f32x4*)feat + i * 2 + 1);
            bf16x8 o;
            #pragma unroll
            for (int j = 0; j < 4; ++j) { o[j] = f2bf(a[j]); o[j + 4] = f2bf(b[j]); }
            ((bf16x8*)featb)[i] = o;   // normal store: want featb LLC-resident
        }
    } else {
        const int mode = block_detect_mode((const uint32_t*)nmask);
        const int bid = blockIdx.x - CVT_BLOCKS;
        if (mode == 0)      pack_loop<0>(nidx, nmask, pidx, bid);
        else if (mode == 1) pack_loop<1>(nidx, nmask, pidx, bid);
        else                pack_loop<2>(nidx, nmask, pidx, bid);
    }
}

__device__ __forceinline__ void stage_weights(const float* __restrict__ wgt,
                                              short* wlds) {
    const int tid = threadIdx.x;
    for (int s = tid; s < KT * 2 * 64; s += 256) {
        const int k    = s >> 7;
        const int rem  = s & 127;
        const int h    = rem >> 6;
        const int l2   = rem & 63;
        const int kg2  = l2 >> 4;
        const int col2 = l2 & 15;
        #pragma unroll
        for (int j = 0; j < 8; ++j)
            wlds[s * 8 + j] = f2bf(wgt[k * 1024 + (kg2 * 8 + j) * 32 + h * 16 + col2]);
    }
}

// fast-path spconv: bf16 features, packed ids, LDS-transposed full-line stores
__global__ __launch_bounds__(256, 8) void spconv_kernel(
    const unsigned short* __restrict__ featb, const float* __restrict__ wgt,
    const int* __restrict__ pidx, unsigned short* __restrict__ yb,
    float* __restrict__ stats)
{
    __shared__ short wlds[KT * 2 * 64 * 8];            // 18 KiB
    __shared__ unsigned short ytile[4][16][32];        // 4 KiB (1KB/wave)
    stage_weights(wgt, wlds);
    __syncthreads();

    const int lane = threadIdx.x & 63;
    const int w    = threadIdx.x >> 6;
    const int col  = lane & 15;
    const int kg   = lane >> 4;
    const int k0   = kg * 8;

    const int gwave = blockIdx.x * 4 + w;
    const int nwave = CONV_BLOCKS * 4;

    float s0 = 0.f, s1 = 0.f, q0 = 0.f, q1 = 0.f;

    for (int t = gwave; t < NTILES; t += nwave) {
        const int vbase = t * 16;
        const int v = vbase + col;

        int ids[KT];
        #pragma unroll
        for (int k = 0; k < KT; ++k)
            ids[k] = __builtin_nontemporal_load(pidx + k * NN + v);

        f32x4 acc0 = {0.f, 0.f, 0.f, 0.f};
        f32x4 acc1 = {0.f, 0.f, 0.f, 0.f};
        #pragma unroll
        for (int k = 0; k < KT; ++k) {
            bf16x8 a = {0, 0, 0, 0, 0, 0, 0, 0};
            if (ids[k] >= 0)
                a = *(const bf16x8*)(featb + (size_t)(unsigned)ids[k] * 32 + k0);
            const bf16x8 b0 = *(const bf16x8*)&wlds[((k * 2 + 0) * 64 + lane) * 8];
            const bf16x8 b1 = *(const bf16x8*)&wlds[((k * 2 + 1) * 64 + lane) * 8];
            acc0 = __builtin_amdgcn_mfma_f32_16x16x32_bf16(a, b0, acc0, 0, 0, 0);
            acc1 = __builtin_amdgcn_mfma_f32_16x16x32_bf16(a, b1, acc1, 0, 0, 0);
        }

        // D layout: col=lane&15, row=(lane>>4)*4+reg (m89-verified).
        // Stage tile in LDS, then one full 16B store per lane (full lines).
        #pragma unroll
        for (int r = 0; r < 4; ++r) {
            const int row = kg * 4 + r;
            float y0 = acc0[r]; y0 = (y0 >= 0.f) ? y0 : NEG_SLOPE * y0;
            float y1 = acc1[r]; y1 = (y1 >= 0.f) ? y1 : NEG_SLOPE * y1;
            ytile[w][row][col]      = (unsigned short)f2bf(y0);
            ytile[w][row][col + 16] = (unsigned short)f2bf(y1);
            s0 += y0; q0 += y0 * y0;
            s1 += y1; q1 += y1 * y1;
        }
        __builtin_amdgcn_wave_barrier();   // wave-synchronous LDS transpose
        const bf16x8 vv = *(const bf16x8*)&ytile[w][lane >> 2][(lane & 3) * 8];
        __builtin_nontemporal_store(vv, (bf16x8*)yb + (size_t)vbase * 4 + lane);
    }

    // reduce across the 4 lanes sharing `col` (l, l^16, l^32, l^48)
    s0 += __shfl_xor(s0, 16); s0 += __shfl_xor(s0, 32);
    s1 += __shfl_xor(s1, 16); s1 += __shfl_xor(s1, 32);
    q0 += __shfl_xor(q0, 16); q0 += __shfl_xor(q0, 32);
    q1 += __shfl_xor(q1, 16); q1 += __shfl_xor(q1, 32);
    __shared__ float red[4][64];
    if (lane < 16) {
        red[w][col]      = s0;  red[w][col + 16] = s1;
        red[w][col + 32] = q0;  red[w][col + 48] = q1;
    }
    __syncthreads();
    if (threadIdx.x < 64) {
        float tot = red[0][threadIdx.x] + red[1][threadIdx.x]
                  + red[2][threadIdx.x] + red[3][threadIdx.x];
        atomicAdd(&stats[(blockIdx.x & (REPS - 1)) * 64 + threadIdx.x], tot);
    }
}

__global__ void bn_stats_kernel(const float* __restrict__ stats,
                                const float* __restrict__ gamma,
                                const float* __restrict__ beta,
                                float* __restrict__ sc) {
    int c = threadIdx.x;
    if (c < 32) {
        float sum = 0.f, sq = 0.f;
        #pragma unroll
        for (int r = 0; r < REPS; ++r) {
            sum += stats[r * 64 + c];
            sq  += stats[r * 64 + 32 + c];
        }
        const float inv_n = 1.0f / (float)NN;
        float mean = sum * inv_n;
        float var  = sq * inv_n - mean * mean;
        float s    = gamma[c] * rsqrtf(var + BN_EPS);
        sc[c]      = s;
        sc[32 + c] = beta[c] - mean * s;
    }
}

__global__ __launch_bounds__(256) void bn_apply_bf_kernel(
    const unsigned short* __restrict__ yb, float* __restrict__ out,
    const float* __restrict__ sc) {
    __shared__ float s[32], b[32];
    if (threadIdx.x < 32)      s[threadIdx.x] = sc[threadIdx.x];
    else if (threadIdx.x < 64) b[threadIdx.x - 32] = sc[threadIdx.x];
    __syncthreads();
    const int tot = NN * 32 / 8;
    for (int i = blockIdx.x * blockDim.x + threadIdx.x; i < tot;
         i += gridDim.x * blockDim.x) {
        const bf16x8 v = __builtin_nontemporal_load((const bf16x8*)yb + i);
        const int c0 = (i & 3) * 8;
        f32x4 o0, o1;
        #pragma unroll
        for (int j = 0; j < 4; ++j) {
            o0[j] = bf2f((unsigned short)v[j])     * s[c0 + j]     + b[c0 + j];
            o1[j] = bf2f((unsigned short)v[j + 4]) * s[c0 + j + 4] + b[c0 + j + 4];
        }
        __builtin_nontemporal_store(o0, (f32x4*)out + i * 2);
        __builtin_nontemporal_store(o1, (f32x4*)out + i * 2 + 1);
    }
}

// ---------------- fallback path (ws too small) — r5-proven ----------------
template <int MODE>
__device__ __forceinline__ bool mask_at(const void* nmask, int e) {
    if (MODE == 0) return ((const uint8_t*)nmask)[e] != 0;
    if (MODE == 1) return ((const int*)nmask)[e] != 0;
    return ((const float*)nmask)[e] != 0.0f;
}

template <int MODE>
__device__ __forceinline__ void conv_f32_loop(
    const float* __restrict__ feat, const int* __restrict__ nidx,
    const void* __restrict__ nmask, float* __restrict__ out,
    const short* wlds, int lane, int col, int kg, int k0,
    int gwave, int nwave, float& s0, float& s1, float& q0, float& q1)
{
    for (int t = gwave; t < NTILES; t += nwave) {
        const int vbase = t * 16;
        const int v = vbase + col;
        int  ids[KT];
        bool act[KT];
        #pragma unroll
        for (int k = 0; k < KT; ++k) {
            const int e = k * NN + v;
            ids[k] = nidx[e];
            act[k] = mask_at<MODE>(nmask, e);
        }
        f32x4 acc0 = {0.f, 0.f, 0.f, 0.f};
        f32x4 acc1 = {0.f, 0.f, 0.f, 0.f};
        #pragma unroll
        for (int k = 0; k < KT; ++k) {
            bf16x8 a = {0, 0, 0, 0, 0, 0, 0, 0};
            if (act[k]) {
                const float* src = feat + (size_t)ids[k] * 32 + k0;
                const f32x4 lo = *(const f32x4*)(src);
                const f32x4 hi = *(const f32x4*)(src + 4);
                #pragma unroll
                for (int j = 0; j < 4; ++j) { a[j] = f2bf(lo[j]); a[j + 4] = f2bf(hi[j]); }
            }
            const bf16x8 b0 = *(const bf16x8*)&wlds[((k * 2 + 0) * 64 + lane) * 8];
            const bf16x8 b1 = *(const bf16x8*)&wlds[((k * 2 + 1) * 64 + lane) * 8];
            acc0 = __builtin_amdgcn_mfma_f32_16x16x32_bf16(a, b0, acc0, 0, 0, 0);
            acc1 = __builtin_amdgcn_mfma_f32_16x16x32_bf16(a, b1, acc1, 0, 0, 0);
        }
        #pragma unroll
        for (int r = 0; r < 4; ++r) {
            const int row = vbase + kg * 4 + r;
            float y0 = acc0[r]; y0 = (y0 >= 0.f) ? y0 : NEG_SLOPE * y0;
            float y1 = acc1[r]; y1 = (y1 >= 0.f) ? y1 : NEG_SLOPE * y1;
            out[row * 32 + col]      = y0;
            out[row * 32 + 16 + col] = y1;
            s0 += y0; q0 += y0 * y0;
            s1 += y1; q1 += y1 * y1;
        }
    }
}

__global__ __launch_bounds__(256, 6) void spconv_f32_kernel(
    const float* __restrict__ feat, const float* __restrict__ wgt,
    const int* __restrict__ nidx, const void* __restrict__ nmask,
    float* __restrict__ out, float* __restrict__ stats)
{
    __shared__ short wlds[KT * 2 * 64 * 8];
    stage_weights(wgt, wlds);
    const int mode = block_detect_mode((const uint32_t*)nmask);
    __syncthreads();
    const int lane = threadIdx.x & 63;
    const int w    = threadIdx.x >> 6;
    const int col  = lane & 15;
    const int kg   = lane >> 4;
    const int k0   = kg * 8;
    const int gwave = blockIdx.x * 4 + w;
    const int nwave = gridDim.x * 4;
    float s0 = 0.f, s1 = 0.f, q0 = 0.f, q1 = 0.f;
    if (mode == 0)
        conv_f32_loop<0>(feat, nidx, nmask, out, wlds, lane, col, kg, k0, gwave, nwave, s0, s1, q0, q1);
    else if (mode == 1)
        conv_f32_loop<1>(feat, nidx, nmask, out, wlds, lane, col, kg, k0, gwave, nwave, s0, s1, q0, q1);
    else
        conv_f32_loop<2>(feat, nidx, nmask, out, wlds, lane, col, kg, k0, gwave, nwave, s0, s1, q0, q1);

    s0 += __shfl_xor(s0, 16); s0 += __shfl_xor(s0, 32);
    s1 += __shfl_xor(s1, 16); s1 += __shfl_xor(s1, 32);
    q0 += __shfl_xor(q0, 16); q0 += __shfl_xor(q0, 32);
    q1 += __shfl_xor(q1, 16); q1 += __shfl_xor(q1, 32);
    __shared__ float red[4][64];
    if (lane < 16) {
        red[w][col]      = s0;  red[w][col + 16] = s1;
        red[w][col + 32] = q0;  red[w][col + 48] = q1;
    }
    __syncthreads();
    if (threadIdx.x < 64) {
        float tot = red[0][threadIdx.x] + red[1][threadIdx.x]
                  + red[2][threadIdx.x] + red[3][threadIdx.x];
        atomicAdd(&stats[(blockIdx.x & (REPS - 1)) * 64 + threadIdx.x], tot);
    }
}

__global__ __launch_bounds__(256) void bn_apply_f32_kernel(
    float* __restrict__ out, const float* __restrict__ sc) {
    __shared__ float s[32], b[32];
    if (threadIdx.x < 32)      s[threadIdx.x] = sc[threadIdx.x];
    else if (threadIdx.x < 64) b[threadIdx.x - 32] = sc[threadIdx.x];
    __syncthreads();
    f32x4* o4 = (f32x4*)out;
    const int total4 = NN * 32 / 4;
    for (int i = blockIdx.x * blockDim.x + threadIdx.x; i < total4;
         i += gridDim.x * blockDim.x) {
        f32x4 v = o4[i];
        const int c0 = (i & 7) * 4;
        #pragma unroll
        for (int j = 0; j < 4; ++j) v[j] = v[j] * s[c0 + j] + b[c0 + j];
        o4[i] = v;
    }
}

extern "C" void kernel_launch(void* const* d_in, const int* in_sizes, int n_in,
                              void* d_out, int out_size, void* d_ws, size_t ws_size,
                              hipStream_t stream) {
    const float* feat  = (const float*)d_in[0];
    const float* wgt   = (const float*)d_in[1];
    const float* gamma = (const float*)d_in[2];
    const float* beta  = (const float*)d_in[3];
    const int*   nidx  = (const int*)d_in[4];
    const void*  nmask = d_in[5];
    float* out = (float*)d_out;

    if (ws_size >= WS_NEEDED) {
        unsigned short* featb = (unsigned short*)d_ws;
        unsigned short* yb    = (unsigned short*)((char*)d_ws + ((size_t)64 << 20));
        float* sc             = (float*)((char*)d_ws + ((size_t)128 << 20));
        int*   pidx           = (int*)d_out;                  // d_out scratch
        float* stats          = out + STATS_F_OFF;            // d_out scratch

        hipMemsetAsync(stats, 0, REPS * 64 * sizeof(float), stream);
        prep_kernel<<<PREP_BLOCKS, 256, 0, stream>>>(feat, featb, nidx, nmask, pidx);
        spconv_kernel<<<CONV_BLOCKS, 256, 0, stream>>>(featb, wgt, pidx, yb, stats);
        bn_stats_kernel<<<1, 64, 0, stream>>>(stats, gamma, beta, sc);
        bn_apply_bf_kernel<<<APPLY_BLOCKS, 256, 0, stream>>>(yb, out, sc);
    } else {
        float* stats = (float*)d_ws;          // REPS*64 floats
        float* sc    = stats + REPS * 64;
        hipMemsetAsync(stats, 0, REPS * 64 * sizeof(float), stream);
        spconv_f32_kernel<<<1536, 256, 0, stream>>>(feat, wgt, nidx, nmask, out, stats);
        bn_stats_kernel<<<1, 64, 0, stream>>>(stats, gamma, beta, sc);
        bn_apply_f32_kernel<<<APPLY_BLOCKS, 256, 0, stream>>>(out, sc);
    }
}

// Round 8
// 421.606 us; speedup vs baseline: 1.3647x; 1.0184x over previous
//
#include <hip/hip_runtime.h>
#include <stdint.h>
#include <stddef.h>

#define NN 1000000
#define KT 9
#define NEG_SLOPE 0.01f
#define BN_EPS 1e-5f
#define NTILES (NN / 16)

#define CVT_BLOCKS 2048
#define PK_BLOCKS 1024
#define PREP_BLOCKS (CVT_BLOCKS + PK_BLOCKS)
#define CONV_BLOCKS 1792            // 7 blocks/CU x 256 CUs, matches LDS residency
#define APPLY_BLOCKS 4096
#define REPS 8

typedef float f32x4 __attribute__((ext_vector_type(4)));
typedef int   i32x4 __attribute__((ext_vector_type(4)));
typedef short bf16x8 __attribute__((ext_vector_type(8)));

// ws layout (fast path): [0,64MB) feat_bf16 [NN][32]; [64MB,128MB) y_bf16;
//   at 128MB: sc[64] floats (scale/shift).
// d_out scratch (fast path): ints [0,9M) = pidx; floats [9M, 9M+512) = stats
//   replicas (8 x {sum[32],sumsq[32]}). Both dead before bn_apply overwrites.
#define META_FLOATS 192
#define WS_NEEDED (((size_t)128 << 20) + META_FLOATS * 4)
#define STATS_F_OFF 9000000   // float index into d_out

__device__ __forceinline__ short f2bf(float f) {
    union { float f; uint32_t u; } x; x.f = f;
    uint32_t u = x.u;
    uint32_t r = (u + 0x7FFFu + ((u >> 16) & 1u)) >> 16;   // RNE
    return (short)(r & 0xFFFFu);
}
__device__ __forceinline__ float bf2f(unsigned short s) {
    union { uint32_t u; float f; } x; x.u = ((uint32_t)s) << 16;
    return x.f;
}

// mode: 0=u8, 1=i32, 2=f32 (detector proven in r1-r2/r5/r7)
__device__ __forceinline__ int block_detect_mode(const uint32_t* __restrict__ mask) {
    __shared__ int md;
    if (threadIdx.x < 64) {
        bool anyf = false, anybig = false;
        #pragma unroll
        for (int j = 0; j < 4; ++j) {
            uint32_t w = mask[threadIdx.x * 4 + j];
            if (w == 0x3F800000u) anyf = true;
            else if (w > 1u) anybig = true;
        }
        unsigned long long bfm = __ballot(anyf);
        unsigned long long bbm = __ballot(anybig);
        if (threadIdx.x == 0) md = bfm ? 2 : (bbm ? 0 : 1);
    }
    __syncthreads();
    return md;
}

template <int MODE>
__device__ __forceinline__ void pack_loop(const int* __restrict__ nidx,
                                          const void* __restrict__ nmask,
                                          int* __restrict__ pidx, int bid) {
    const int tot4 = KT * NN / 4;   // 2,250,000
    for (int i = bid * 256 + threadIdx.x; i < tot4; i += PK_BLOCKS * 256) {
        const i32x4 id4 = __builtin_nontemporal_load((const i32x4*)nidx + i);
        i32x4 o;
        if (MODE == 0) {
            const uint32_t mw = __builtin_nontemporal_load((const uint32_t*)nmask + i);
            #pragma unroll
            for (int j = 0; j < 4; ++j) o[j] = ((mw >> (8 * j)) & 0xFFu) ? id4[j] : -1;
        } else if (MODE == 1) {
            const i32x4 m4 = __builtin_nontemporal_load((const i32x4*)nmask + i);
            #pragma unroll
            for (int j = 0; j < 4; ++j) o[j] = m4[j] ? id4[j] : -1;
        } else {
            const f32x4 m4 = __builtin_nontemporal_load((const f32x4*)nmask + i);
            #pragma unroll
            for (int j = 0; j < 4; ++j) o[j] = (m4[j] != 0.0f) ? id4[j] : -1;
        }
        ((i32x4*)pidx)[i] = o;
    }
}

// prep: blocks [0,CVT_BLOCKS) convert features f32->bf16; rest pack idx+mask.
__global__ __launch_bounds__(256) void prep_kernel(
    const float* __restrict__ feat, unsigned short* __restrict__ featb,
    const int* __restrict__ nidx, const void* __restrict__ nmask,
    int* __restrict__ pidx)
{
    if (blockIdx.x < CVT_BLOCKS) {
        const int tot = NN * 32 / 8;   // 4,000,000
        for (int i = blockIdx.x * 256 + threadIdx.x; i < tot; i += CVT_BLOCKS * 256) {
            const f32x4 a = __builtin_nontemporal_load((const f32x4*)feat + i * 2);
            const f32x4 b = __builtin_nontemporal_load((const f32x4*)feat + i * 2 + 1);
            bf16x8 o;
            #pragma unroll
            for (int j = 0; j < 4; ++j) { o[j] = f2bf(a[j]); o[j + 4] = f2bf(b[j]); }
            ((bf16x8*)featb)[i] = o;   // normal store: want featb LLC-resident
        }
    } else {
        const int mode = block_detect_mode((const uint32_t*)nmask);
        const int bid = blockIdx.x - CVT_BLOCKS;
        if (mode == 0)      pack_loop<0>(nidx, nmask, pidx, bid);
        else if (mode == 1) pack_loop<1>(nidx, nmask, pidx, bid);
        else                pack_loop<2>(nidx, nmask, pidx, bid);
    }
}

__device__ __forceinline__ void stage_weights(const float* __restrict__ wgt,
                                              short* wlds) {
    const int tid = threadIdx.x;
    for (int s = tid; s < KT * 2 * 64; s += 256) {
        const int k    = s >> 7;
        const int rem  = s & 127;
        const int h    = rem >> 6;
        const int l2   = rem & 63;
        const int kg2  = l2 >> 4;
        const int col2 = l2 & 15;
        #pragma unroll
        for (int j = 0; j < 8; ++j)
            wlds[s * 8 + j] = f2bf(wgt[k * 1024 + (kg2 * 8 + j) * 32 + h * 16 + col2]);
    }
}

// fast-path spconv: bf16 features, packed ids, LDS-transposed full-line stores,
// pidx software-pipelined across tiles, red/ytile LDS union -> 22.5 KB -> 7 blk/CU
__global__ __launch_bounds__(256, 7) void spconv_kernel(
    const unsigned short* __restrict__ featb, const float* __restrict__ wgt,
    const int* __restrict__ pidx, unsigned short* __restrict__ yb,
    float* __restrict__ stats)
{
    __shared__ short wlds[KT * 2 * 64 * 8];            // 18 KiB
    __shared__ __align__(16) unsigned char scr[4 * 16 * 32 * 2];   // 4 KiB union
    unsigned short (*ytile)[16][32] = (unsigned short (*)[16][32])scr;
    float (*red)[64] = (float (*)[64])scr;
    stage_weights(wgt, wlds);
    __syncthreads();

    const int lane = threadIdx.x & 63;
    const int w    = threadIdx.x >> 6;
    const int col  = lane & 15;
    const int kg   = lane >> 4;
    const int k0   = kg * 8;

    const int gwave = blockIdx.x * 4 + w;
    const int nwave = CONV_BLOCKS * 4;

    float s0 = 0.f, s1 = 0.f, q0 = 0.f, q1 = 0.f;

    int ids[KT];
    if (gwave < NTILES) {
        const int v0 = gwave * 16 + col;
        #pragma unroll
        for (int k = 0; k < KT; ++k)
            ids[k] = __builtin_nontemporal_load(pidx + k * NN + v0);
    }

    for (int t = gwave; t < NTILES; t += nwave) {
        const int vbase = t * 16;

        // prefetch next tile's ids (hides pidx HBM latency under this tile)
        int idsn[KT];
        const int tn = t + nwave;
        if (tn < NTILES) {
            const int vn = tn * 16 + col;
            #pragma unroll
            for (int k = 0; k < KT; ++k)
                idsn[k] = __builtin_nontemporal_load(pidx + k * NN + vn);
        }

        f32x4 acc0 = {0.f, 0.f, 0.f, 0.f};
        f32x4 acc1 = {0.f, 0.f, 0.f, 0.f};
        #pragma unroll
        for (int k = 0; k < KT; ++k) {
            bf16x8 a = {0, 0, 0, 0, 0, 0, 0, 0};
            if (ids[k] >= 0)
                a = *(const bf16x8*)(featb + (size_t)(unsigned)ids[k] * 32 + k0);
            const bf16x8 b0 = *(const bf16x8*)&wlds[((k * 2 + 0) * 64 + lane) * 8];
            const bf16x8 b1 = *(const bf16x8*)&wlds[((k * 2 + 1) * 64 + lane) * 8];
            acc0 = __builtin_amdgcn_mfma_f32_16x16x32_bf16(a, b0, acc0, 0, 0, 0);
            acc1 = __builtin_amdgcn_mfma_f32_16x16x32_bf16(a, b1, acc1, 0, 0, 0);
        }

        // D layout: col=lane&15, row=(lane>>4)*4+reg (m89-verified).
        // Stage tile in LDS, then one full 16B store per lane (full lines).
        #pragma unroll
        for (int r = 0; r < 4; ++r) {
            const int row = kg * 4 + r;
            float y0 = acc0[r]; y0 = (y0 >= 0.f) ? y0 : NEG_SLOPE * y0;
            float y1 = acc1[r]; y1 = (y1 >= 0.f) ? y1 : NEG_SLOPE * y1;
            ytile[w][row][col]      = (unsigned short)f2bf(y0);
            ytile[w][row][col + 16] = (unsigned short)f2bf(y1);
            s0 += y0; q0 += y0 * y0;
            s1 += y1; q1 += y1 * y1;
        }
        __builtin_amdgcn_wave_barrier();   // wave-synchronous LDS transpose
        const bf16x8 vv = *(const bf16x8*)&ytile[w][lane >> 2][(lane & 3) * 8];
        __builtin_nontemporal_store(vv, (bf16x8*)yb + (size_t)vbase * 4 + lane);

        #pragma unroll
        for (int k = 0; k < KT; ++k) ids[k] = idsn[k];
    }

    __syncthreads();   // all waves out of loop before red aliases ytile

    // reduce across the 4 lanes sharing `col` (l, l^16, l^32, l^48)
    s0 += __shfl_xor(s0, 16); s0 += __shfl_xor(s0, 32);
    s1 += __shfl_xor(s1, 16); s1 += __shfl_xor(s1, 32);
    q0 += __shfl_xor(q0, 16); q0 += __shfl_xor(q0, 32);
    q1 += __shfl_xor(q1, 16); q1 += __shfl_xor(q1, 32);
    if (lane < 16) {
        red[w][col]      = s0;  red[w][col + 16] = s1;
        red[w][col + 32] = q0;  red[w][col + 48] = q1;
    }
    __syncthreads();
    if (threadIdx.x < 64) {
        float tot = red[0][threadIdx.x] + red[1][threadIdx.x]
                  + red[2][threadIdx.x] + red[3][threadIdx.x];
        atomicAdd(&stats[(blockIdx.x & (REPS - 1)) * 64 + threadIdx.x], tot);
    }
}

__global__ void bn_stats_kernel(const float* __restrict__ stats,
                                const float* __restrict__ gamma,
                                const float* __restrict__ beta,
                                float* __restrict__ sc) {
    int c = threadIdx.x;
    if (c < 32) {
        float sum = 0.f, sq = 0.f;
        #pragma unroll
        for (int r = 0; r < REPS; ++r) {
            sum += stats[r * 64 + c];
            sq  += stats[r * 64 + 32 + c];
        }
        const float inv_n = 1.0f / (float)NN;
        float mean = sum * inv_n;
        float var  = sq * inv_n - mean * mean;
        float s    = gamma[c] * rsqrtf(var + BN_EPS);
        sc[c]      = s;
        sc[32 + c] = beta[c] - mean * s;
    }
}

__global__ __launch_bounds__(256) void bn_apply_bf_kernel(
    const unsigned short* __restrict__ yb, float* __restrict__ out,
    const float* __restrict__ sc) {
    __shared__ float s[32], b[32];
    if (threadIdx.x < 32)      s[threadIdx.x] = sc[threadIdx.x];
    else if (threadIdx.x < 64) b[threadIdx.x - 32] = sc[threadIdx.x];
    __syncthreads();
    const int tot = NN * 32 / 8;
    for (int i = blockIdx.x * blockDim.x + threadIdx.x; i < tot;
         i += gridDim.x * blockDim.x) {
        const bf16x8 v = __builtin_nontemporal_load((const bf16x8*)yb + i);
        const int c0 = (i & 3) * 8;
        f32x4 o0, o1;
        #pragma unroll
        for (int j = 0; j < 4; ++j) {
            o0[j] = bf2f((unsigned short)v[j])     * s[c0 + j]     + b[c0 + j];
            o1[j] = bf2f((unsigned short)v[j + 4]) * s[c0 + j + 4] + b[c0 + j + 4];
        }
        __builtin_nontemporal_store(o0, (f32x4*)out + i * 2);
        __builtin_nontemporal_store(o1, (f32x4*)out + i * 2 + 1);
    }
}

// ---------------- fallback path (ws too small) — r5-proven ----------------
template <int MODE>
__device__ __forceinline__ bool mask_at(const void* nmask, int e) {
    if (MODE == 0) return ((const uint8_t*)nmask)[e] != 0;
    if (MODE == 1) return ((const int*)nmask)[e] != 0;
    return ((const float*)nmask)[e] != 0.0f;
}

template <int MODE>
__device__ __forceinline__ void conv_f32_loop(
    const float* __restrict__ feat, const int* __restrict__ nidx,
    const void* __restrict__ nmask, float* __restrict__ out,
    const short* wlds, int lane, int col, int kg, int k0,
    int gwave, int nwave, float& s0, float& s1, float& q0, float& q1)
{
    for (int t = gwave; t < NTILES; t += nwave) {
        const int vbase = t * 16;
        const int v = vbase + col;
        int  ids[KT];
        bool act[KT];
        #pragma unroll
        for (int k = 0; k < KT; ++k) {
            const int e = k * NN + v;
            ids[k] = nidx[e];
            act[k] = mask_at<MODE>(nmask, e);
        }
        f32x4 acc0 = {0.f, 0.f, 0.f, 0.f};
        f32x4 acc1 = {0.f, 0.f, 0.f, 0.f};
        #pragma unroll
        for (int k = 0; k < KT; ++k) {
            bf16x8 a = {0, 0, 0, 0, 0, 0, 0, 0};
            if (act[k]) {
                const float* src = feat + (size_t)ids[k] * 32 + k0;
                const f32x4 lo = *(const f32x4*)(src);
                const f32x4 hi = *(const f32x4*)(src + 4);
                #pragma unroll
                for (int j = 0; j < 4; ++j) { a[j] = f2bf(lo[j]); a[j + 4] = f2bf(hi[j]); }
            }
            const bf16x8 b0 = *(const bf16x8*)&wlds[((k * 2 + 0) * 64 + lane) * 8];
            const bf16x8 b1 = *(const bf16x8*)&wlds[((k * 2 + 1) * 64 + lane) * 8];
            acc0 = __builtin_amdgcn_mfma_f32_16x16x32_bf16(a, b0, acc0, 0, 0, 0);
            acc1 = __builtin_amdgcn_mfma_f32_16x16x32_bf16(a, b1, acc1, 0, 0, 0);
        }
        #pragma unroll
        for (int r = 0; r < 4; ++r) {
            const int row = vbase + kg * 4 + r;
            float y0 = acc0[r]; y0 = (y0 >= 0.f) ? y0 : NEG_SLOPE * y0;
            float y1 = acc1[r]; y1 = (y1 >= 0.f) ? y1 : NEG_SLOPE * y1;
            out[row * 32 + col]      = y0;
            out[row * 32 + 16 + col] = y1;
            s0 += y0; q0 += y0 * y0;
            s1 += y1; q1 += y1 * y1;
        }
    }
}

__global__ __launch_bounds__(256, 6) void spconv_f32_kernel(
    const float* __restrict__ feat, const float* __restrict__ wgt,
    const int* __restrict__ nidx, const void* __restrict__ nmask,
    float* __restrict__ out, float* __restrict__ stats)
{
    __shared__ short wlds[KT * 2 * 64 * 8];
    stage_weights(wgt, wlds);
    const int mode = block_detect_mode((const uint32_t*)nmask);
    __syncthreads();
    const int lane = threadIdx.x & 63;
    const int w    = threadIdx.x >> 6;
    const int col  = lane & 15;
    const int kg   = lane >> 4;
    const int k0   = kg * 8;
    const int gwave = blockIdx.x * 4 + w;
    const int nwave = gridDim.x * 4;
    float s0 = 0.f, s1 = 0.f, q0 = 0.f, q1 = 0.f;
    if (mode == 0)
        conv_f32_loop<0>(feat, nidx, nmask, out, wlds, lane, col, kg, k0, gwave, nwave, s0, s1, q0, q1);
    else if (mode == 1)
        conv_f32_loop<1>(feat, nidx, nmask, out, wlds, lane, col, kg, k0, gwave, nwave, s0, s1, q0, q1);
    else
        conv_f32_loop<2>(feat, nidx, nmask, out, wlds, lane, col, kg, k0, gwave, nwave, s0, s1, q0, q1);

    s0 += __shfl_xor(s0, 16); s0 += __shfl_xor(s0, 32);
    s1 += __shfl_xor(s1, 16); s1 += __shfl_xor(s1, 32);
    q0 += __shfl_xor(q0, 16); q0 += __shfl_xor(q0, 32);
    q1 += __shfl_xor(q1, 16); q1 += __shfl_xor(q1, 32);
    __shared__ float red[4][64];
    if (lane < 16) {
        red[w][col]      = s0;  red[w][col + 16] = s1;
        red[w][col + 32] = q0;  red[w][col + 48] = q1;
    }
    __syncthreads();
    if (threadIdx.x < 64) {
        float tot = red[0][threadIdx.x] + red[1][threadIdx.x]
                  + red[2][threadIdx.x] + red[3][threadIdx.x];
        atomicAdd(&stats[(blockIdx.x & (REPS - 1)) * 64 + threadIdx.x], tot);
    }
}

__global__ __launch_bounds__(256) void bn_apply_f32_kernel(
    float* __restrict__ out, const float* __restrict__ sc) {
    __shared__ float s[32], b[32];
    if (threadIdx.x < 32)      s[threadIdx.x] = sc[threadIdx.x];
    else if (threadIdx.x < 64) b[threadIdx.x - 32] = sc[threadIdx.x];
    __syncthreads();
    f32x4* o4 = (f32x4*)out;
    const int total4 = NN * 32 / 4;
    for (int i = blockIdx.x * blockDim.x + threadIdx.x; i < total4;
         i += gridDim.x * blockDim.x) {
        f32x4 v = o4[i];
        const int c0 = (i & 7) * 4;
        #pragma unroll
        for (int j = 0; j < 4; ++j) v[j] = v[j] * s[c0 + j] + b[c0 + j];
        o4[i] = v;
    }
}

extern "C" void kernel_launch(void* const* d_in, const int* in_sizes, int n_in,
                              void* d_out, int out_size, void* d_ws, size_t ws_size,
                              hipStream_t stream) {
    const float* feat  = (const float*)d_in[0];
    const float* wgt   = (const float*)d_in[1];
    const float* gamma = (const float*)d_in[2];
    const float* beta  = (const float*)d_in[3];
    const int*   nidx  = (const int*)d_in[4];
    const void*  nmask = d_in[5];
    float* out = (float*)d_out;

    if (ws_size >= WS_NEEDED) {
        unsigned short* featb = (unsigned short*)d_ws;
        unsigned short* yb    = (unsigned short*)((char*)d_ws + ((size_t)64 << 20));
        float* sc             = (float*)((char*)d_ws + ((size_t)128 << 20));
        int*   pidx           = (int*)d_out;                  // d_out scratch
        float* stats          = out + STATS_F_OFF;            // d_out scratch

        hipMemsetAsync(stats, 0, REPS * 64 * sizeof(float), stream);
        prep_kernel<<<PREP_BLOCKS, 256, 0, stream>>>(feat, featb, nidx, nmask, pidx);
        spconv_kernel<<<CONV_BLOCKS, 256, 0, stream>>>(featb, wgt, pidx, yb, stats);
        bn_stats_kernel<<<1, 64, 0, stream>>>(stats, gamma, beta, sc);
        bn_apply_bf_kernel<<<APPLY_BLOCKS, 256, 0, stream>>>(yb, out, sc);
    } else {
        float* stats = (float*)d_ws;          // REPS*64 floats
        float* sc    = stats + REPS * 64;
        hipMemsetAsync(stats, 0, REPS * 64 * sizeof(float), stream);
        spconv_f32_kernel<<<1536, 256, 0, stream>>>(feat, wgt, nidx, nmask, out, stats);
        bn_stats_kernel<<<1, 64, 0, stream>>>(stats, gamma, beta, sc);
        bn_apply_f32_kernel<<<APPLY_BLOCKS, 256, 0, stream>>>(out, sc);
    }
}